// Round 1
// baseline (3337.625 us; speedup 1.0000x reference)
//
#include <hip/hip_runtime.h>
#include <math.h>

#define B_N 32768
#define IN_DIM 1024
#define HID 64
#define D_DIM 512
#define P_N 2048

// ---------------------------------------------------------------------------
// K1: h1 = relu(x @ W0^T + b0)   [B,1024] -> [B,64]
// BM=128, BN=64 (full), BK=32, 256 threads, microtile 8x4
// ---------------------------------------------------------------------------
__global__ __launch_bounds__(256) void k_enc1(const float* __restrict__ x,
                                              const float* __restrict__ W0,
                                              const float* __restrict__ b0,
                                              float* __restrict__ h1) {
    __shared__ float As[128][33];
    __shared__ float Ws[64][33];
    const int tid = threadIdx.x;
    const int tx = tid & 15, ty = tid >> 4;
    const int bm = blockIdx.x * 128;

    float acc[8][4] = {};
    for (int k0 = 0; k0 < IN_DIM; k0 += 32) {
#pragma unroll
        for (int i = 0; i < 4; ++i) {
            int li = tid + i * 256;
            int r = li >> 3, c = (li & 7) << 2;
            float4 v = *(const float4*)(x + (size_t)(bm + r) * IN_DIM + k0 + c);
            As[r][c] = v.x; As[r][c + 1] = v.y; As[r][c + 2] = v.z; As[r][c + 3] = v.w;
        }
#pragma unroll
        for (int i = 0; i < 2; ++i) {
            int li = tid + i * 256;
            int r = li >> 3, c = (li & 7) << 2;
            float4 v = *(const float4*)(W0 + (size_t)r * IN_DIM + k0 + c);
            Ws[r][c] = v.x; Ws[r][c + 1] = v.y; Ws[r][c + 2] = v.z; Ws[r][c + 3] = v.w;
        }
        __syncthreads();
#pragma unroll 16
        for (int kk = 0; kk < 32; ++kk) {
            float a[8], w[4];
#pragma unroll
            for (int i = 0; i < 8; ++i) a[i] = As[ty * 8 + i][kk];
#pragma unroll
            for (int j = 0; j < 4; ++j) w[j] = Ws[tx * 4 + j][kk];
#pragma unroll
            for (int i = 0; i < 8; ++i)
#pragma unroll
                for (int j = 0; j < 4; ++j)
                    acc[i][j] = fmaf(a[i], w[j], acc[i][j]);
        }
        __syncthreads();
    }
#pragma unroll
    for (int i = 0; i < 8; ++i) {
        int r = bm + ty * 8 + i;
        float4 o;
        float b;
        b = b0[tx * 4 + 0]; o.x = fmaxf(acc[i][0] + b, 0.f);
        b = b0[tx * 4 + 1]; o.y = fmaxf(acc[i][1] + b, 0.f);
        b = b0[tx * 4 + 2]; o.z = fmaxf(acc[i][2] + b, 0.f);
        b = b0[tx * 4 + 3]; o.w = fmaxf(acc[i][3] + b, 0.f);
        *(float4*)(h1 + (size_t)r * HID + tx * 4) = o;
    }
}

// ---------------------------------------------------------------------------
// K2: h2 = relu(h1 @ W1^T + b1)   [B,64] -> [B,512]
// BM=128, BN=128, BK=64 (single pass), 256 threads, microtile 8x8 (split cols)
// ---------------------------------------------------------------------------
__global__ __launch_bounds__(256) void k_enc2(const float* __restrict__ h1,
                                              const float* __restrict__ W1,
                                              const float* __restrict__ b1,
                                              float* __restrict__ h2) {
    __shared__ float As[128][65];
    __shared__ float Ws[128][65];
    const int tid = threadIdx.x;
    const int tx = tid & 15, ty = tid >> 4;
    const int bm = blockIdx.x * 128;
    const int bn = blockIdx.y * 128;

#pragma unroll
    for (int i = 0; i < 8; ++i) {
        int li = tid + i * 256;
        int r = li >> 4, c = (li & 15) << 2;
        float4 v = *(const float4*)(h1 + (size_t)(bm + r) * HID + c);
        As[r][c] = v.x; As[r][c + 1] = v.y; As[r][c + 2] = v.z; As[r][c + 3] = v.w;
    }
#pragma unroll
    for (int i = 0; i < 8; ++i) {
        int li = tid + i * 256;
        int r = li >> 4, c = (li & 15) << 2;
        float4 v = *(const float4*)(W1 + (size_t)(bn + r) * HID + c);
        Ws[r][c] = v.x; Ws[r][c + 1] = v.y; Ws[r][c + 2] = v.z; Ws[r][c + 3] = v.w;
    }
    __syncthreads();

    float acc[8][8] = {};
#pragma unroll 16
    for (int kk = 0; kk < 64; ++kk) {
        float a[8], w[8];
#pragma unroll
        for (int i = 0; i < 8; ++i) a[i] = As[ty * 8 + i][kk];
#pragma unroll
        for (int j = 0; j < 4; ++j) {
            w[j] = Ws[tx * 4 + j][kk];
            w[4 + j] = Ws[64 + tx * 4 + j][kk];
        }
#pragma unroll
        for (int i = 0; i < 8; ++i)
#pragma unroll
            for (int j = 0; j < 8; ++j)
                acc[i][j] = fmaf(a[i], w[j], acc[i][j]);
    }

#pragma unroll
    for (int i = 0; i < 8; ++i) {
        int r = bm + ty * 8 + i;
        float4 o;
        o.x = fmaxf(acc[i][0] + b1[bn + tx * 4 + 0], 0.f);
        o.y = fmaxf(acc[i][1] + b1[bn + tx * 4 + 1], 0.f);
        o.z = fmaxf(acc[i][2] + b1[bn + tx * 4 + 2], 0.f);
        o.w = fmaxf(acc[i][3] + b1[bn + tx * 4 + 3], 0.f);
        *(float4*)(h2 + (size_t)r * D_DIM + bn + tx * 4) = o;
        o.x = fmaxf(acc[i][4] + b1[bn + 64 + tx * 4 + 0], 0.f);
        o.y = fmaxf(acc[i][5] + b1[bn + 64 + tx * 4 + 1], 0.f);
        o.z = fmaxf(acc[i][6] + b1[bn + 64 + tx * 4 + 2], 0.f);
        o.w = fmaxf(acc[i][7] + b1[bn + 64 + tx * 4 + 3], 0.f);
        *(float4*)(h2 + (size_t)r * D_DIM + bn + 64 + tx * 4) = o;
    }
}

// ---------------------------------------------------------------------------
// K3: mu = h2@Wmu^T+bmu ; lv = h2@Wvar^T+bvar ; latents = mu + eps*exp(lv/2)
//     + KL partial sums.  BM=128, BN=64, BK=64, 256 threads, 8x4 x2 microtile
// ---------------------------------------------------------------------------
__global__ __launch_bounds__(256) void k_muvar(const float* __restrict__ h2,
                                               const float* __restrict__ Wmu,
                                               const float* __restrict__ bmu,
                                               const float* __restrict__ Wvar,
                                               const float* __restrict__ bvar,
                                               const float* __restrict__ eps,
                                               float* __restrict__ latents,
                                               float* __restrict__ div_acc) {
    __shared__ float As[128][65];
    __shared__ float Wm[64][65];
    __shared__ float Wv[64][65];
    const int tid = threadIdx.x;
    const int tx = tid & 15, ty = tid >> 4;
    const int bm = blockIdx.x * 128;
    const int bn = blockIdx.y * 64;

    float am[8][4] = {}, av[8][4] = {};
    for (int k0 = 0; k0 < D_DIM; k0 += 64) {
#pragma unroll
        for (int i = 0; i < 8; ++i) {
            int li = tid + i * 256;
            int r = li >> 4, c = (li & 15) << 2;
            float4 v = *(const float4*)(h2 + (size_t)(bm + r) * D_DIM + k0 + c);
            As[r][c] = v.x; As[r][c + 1] = v.y; As[r][c + 2] = v.z; As[r][c + 3] = v.w;
        }
#pragma unroll
        for (int i = 0; i < 4; ++i) {
            int li = tid + i * 256;
            int r = li >> 4, c = (li & 15) << 2;
            float4 v = *(const float4*)(Wmu + (size_t)(bn + r) * D_DIM + k0 + c);
            Wm[r][c] = v.x; Wm[r][c + 1] = v.y; Wm[r][c + 2] = v.z; Wm[r][c + 3] = v.w;
            float4 u = *(const float4*)(Wvar + (size_t)(bn + r) * D_DIM + k0 + c);
            Wv[r][c] = u.x; Wv[r][c + 1] = u.y; Wv[r][c + 2] = u.z; Wv[r][c + 3] = u.w;
        }
        __syncthreads();
#pragma unroll 16
        for (int kk = 0; kk < 64; ++kk) {
            float a[8], wm[4], wv[4];
#pragma unroll
            for (int i = 0; i < 8; ++i) a[i] = As[ty * 8 + i][kk];
#pragma unroll
            for (int j = 0; j < 4; ++j) {
                wm[j] = Wm[tx * 4 + j][kk];
                wv[j] = Wv[tx * 4 + j][kk];
            }
#pragma unroll
            for (int i = 0; i < 8; ++i)
#pragma unroll
                for (int j = 0; j < 4; ++j) {
                    am[i][j] = fmaf(a[i], wm[j], am[i][j]);
                    av[i][j] = fmaf(a[i], wv[j], av[i][j]);
                }
        }
        __syncthreads();
    }

    float kl = 0.f;
#pragma unroll
    for (int i = 0; i < 8; ++i) {
        int r = bm + ty * 8 + i;
        int c = bn + tx * 4;
        float4 ev = *(const float4*)(eps + (size_t)r * D_DIM + c);
        float4 o;
        {
            float mu = am[i][0] + bmu[c + 0];
            float lv = av[i][0] + bvar[c + 0];
            float el = __expf(lv);
            o.x = fmaf(ev.x, __expf(0.5f * lv), mu);
            kl += mu * mu + el - lv - 1.f;
        }
        {
            float mu = am[i][1] + bmu[c + 1];
            float lv = av[i][1] + bvar[c + 1];
            float el = __expf(lv);
            o.y = fmaf(ev.y, __expf(0.5f * lv), mu);
            kl += mu * mu + el - lv - 1.f;
        }
        {
            float mu = am[i][2] + bmu[c + 2];
            float lv = av[i][2] + bvar[c + 2];
            float el = __expf(lv);
            o.z = fmaf(ev.z, __expf(0.5f * lv), mu);
            kl += mu * mu + el - lv - 1.f;
        }
        {
            float mu = am[i][3] + bmu[c + 3];
            float lv = av[i][3] + bvar[c + 3];
            float el = __expf(lv);
            o.w = fmaf(ev.w, __expf(0.5f * lv), mu);
            kl += mu * mu + el - lv - 1.f;
        }
        *(float4*)(latents + (size_t)r * D_DIM + c) = o;
    }
    kl *= 0.5f;
#pragma unroll
    for (int m = 1; m < 64; m <<= 1) kl += __shfl_xor(kl, m);
    __shared__ float red[4];
    if ((tid & 63) == 0) red[tid >> 6] = kl;
    __syncthreads();
    if (tid == 0) atomicAdd(div_acc, red[0] + red[1] + red[2] + red[3]);
}

// ---------------------------------------------------------------------------
// K4a: pnorm[p] = sum_d protos[p,d]^2   (one wave per proto)
// ---------------------------------------------------------------------------
__global__ __launch_bounds__(256) void k_pnorm(const float* __restrict__ protos,
                                               float* __restrict__ pnorm) {
    const int p = blockIdx.x * 4 + (threadIdx.x >> 6);
    const int lane = threadIdx.x & 63;
    const float* row = protos + (size_t)p * D_DIM;
    float4 v1 = *(const float4*)(row + lane * 8);
    float4 v2 = *(const float4*)(row + lane * 8 + 4);
    float s = v1.x * v1.x + v1.y * v1.y + v1.z * v1.z + v1.w * v1.w +
              v2.x * v2.x + v2.y * v2.y + v2.z * v2.z + v2.w * v2.w;
#pragma unroll
    for (int m = 1; m < 64; m <<= 1) s += __shfl_xor(s, m);
    if (lane == 0) pnorm[p] = s;
}

// ---------------------------------------------------------------------------
// K4: per row: G[p] = 2*l.p - |p|^2 over all 2048 protos.
// sweep0: running (max, sumexp) + argmax -> lse, idx
// sweep1: recompute G, accumulate exp(G - lse) into soft_dist
// Block = 64 rows, proto tile 128, BK=64. 256 thr: 16(tx, protos) x 16(ty, rows)
// Each thread: 4 rows x 8 protos (cols split as tx*4+j and 64+tx*4+j).
// ---------------------------------------------------------------------------
__global__ __launch_bounds__(256) void k_vq(const float* __restrict__ latents,
                                            const float* __restrict__ protos,
                                            const float* __restrict__ pnorm,
                                            int* __restrict__ idxOut,
                                            float* __restrict__ soft_acc) {
    __shared__ float Ls[64][65];
    __shared__ float Ps[128][65];
    __shared__ float soft_l[P_N];
    const int tid = threadIdx.x;
    const int tx = tid & 15, ty = tid >> 4;
    const int bm = blockIdx.x * 64;

    for (int i = tid; i < P_N; i += 256) soft_l[i] = 0.f;

    float m_run[4], s_run[4];
    int bidx[4];
    float lse[4];
#pragma unroll
    for (int i = 0; i < 4; ++i) { m_run[i] = -INFINITY; s_run[i] = 0.f; bidx[i] = 0; }

    for (int sweep = 0; sweep < 2; ++sweep) {
        if (sweep == 1) {
#pragma unroll
            for (int i = 0; i < 4; ++i) lse[i] = m_run[i] + __logf(s_run[i]);
            if (tx == 0) {
#pragma unroll
                for (int i = 0; i < 4; ++i) idxOut[bm + ty * 4 + i] = bidx[i];
            }
        }
        for (int pt = 0; pt < P_N; pt += 128) {
            float acc[4][8] = {};
            for (int k0 = 0; k0 < D_DIM; k0 += 64) {
#pragma unroll
                for (int i = 0; i < 4; ++i) {
                    int li = tid + i * 256;
                    int r = li >> 4, c = (li & 15) << 2;
                    float4 v = *(const float4*)(latents + (size_t)(bm + r) * D_DIM + k0 + c);
                    Ls[r][c] = v.x; Ls[r][c + 1] = v.y; Ls[r][c + 2] = v.z; Ls[r][c + 3] = v.w;
                }
#pragma unroll
                for (int i = 0; i < 8; ++i) {
                    int li = tid + i * 256;
                    int r = li >> 4, c = (li & 15) << 2;
                    float4 v = *(const float4*)(protos + (size_t)(pt + r) * D_DIM + k0 + c);
                    Ps[r][c] = v.x; Ps[r][c + 1] = v.y; Ps[r][c + 2] = v.z; Ps[r][c + 3] = v.w;
                }
                __syncthreads();
#pragma unroll 16
                for (int kk = 0; kk < 64; ++kk) {
                    float a[4], w[8];
#pragma unroll
                    for (int i = 0; i < 4; ++i) a[i] = Ls[ty * 4 + i][kk];
#pragma unroll
                    for (int j = 0; j < 4; ++j) {
                        w[j] = Ps[tx * 4 + j][kk];
                        w[4 + j] = Ps[64 + tx * 4 + j][kk];
                    }
#pragma unroll
                    for (int i = 0; i < 4; ++i)
#pragma unroll
                        for (int j = 0; j < 8; ++j)
                            acc[i][j] = fmaf(a[i], w[j], acc[i][j]);
                }
                __syncthreads();
            }
            // finalize tile: G = 2*acc - pnorm
            float pn[8];
#pragma unroll
            for (int j = 0; j < 4; ++j) {
                pn[j] = pnorm[pt + tx * 4 + j];
                pn[4 + j] = pnorm[pt + 64 + tx * 4 + j];
            }
            float g[4][8];
#pragma unroll
            for (int i = 0; i < 4; ++i)
#pragma unroll
                for (int j = 0; j < 8; ++j)
                    g[i][j] = 2.f * acc[i][j] - pn[j];

            if (sweep == 0) {
#pragma unroll
                for (int i = 0; i < 4; ++i) {
                    // local argmax over this thread's 8 protos (tie -> smaller idx)
                    float mv = g[i][0];
                    int mi = pt + tx * 4;
#pragma unroll
                    for (int j = 1; j < 8; ++j) {
                        int gj = (j < 4) ? (pt + tx * 4 + j) : (pt + 64 + tx * 4 + (j - 4));
                        if (g[i][j] > mv || (g[i][j] == mv && gj < mi)) { mv = g[i][j]; mi = gj; }
                    }
                    // reduce across the 16 lanes of this row group
#pragma unroll
                    for (int m = 1; m < 16; m <<= 1) {
                        float ov = __shfl_xor(mv, m);
                        int oi = __shfl_xor(mi, m);
                        if (ov > mv || (ov == mv && oi < mi)) { mv = ov; mi = oi; }
                    }
                    // tile sumexp with tile max mv
                    float se = 0.f;
#pragma unroll
                    for (int j = 0; j < 8; ++j) se += __expf(g[i][j] - mv);
#pragma unroll
                    for (int m = 1; m < 16; m <<= 1) se += __shfl_xor(se, m);
                    // merge into running stats
                    float mnew = fmaxf(m_run[i], mv);
                    s_run[i] = s_run[i] * __expf(m_run[i] - mnew) + se * __expf(mv - mnew);
                    if (mv > m_run[i] || (mv == m_run[i] && mi < bidx[i])) bidx[i] = mi;
                    if (!(m_run[i] >= mv)) { /* keep argmax consistent: handled above */ }
                    m_run[i] = mnew;
                }
            } else {
                float c0[8] = {};
#pragma unroll
                for (int i = 0; i < 4; ++i)
#pragma unroll
                    for (int j = 0; j < 8; ++j)
                        c0[j] += __expf(g[i][j] - lse[i]);
#pragma unroll
                for (int j = 0; j < 4; ++j) {
                    atomicAdd(&soft_l[pt + tx * 4 + j], c0[j]);
                    atomicAdd(&soft_l[pt + 64 + tx * 4 + j], c0[4 + j]);
                }
            }
        }
    }
    __syncthreads();
    for (int i = tid; i < P_N; i += 256) atomicAdd(&soft_acc[i], soft_l[i]);
}

// ---------------------------------------------------------------------------
// K5: out[r,:] = protos[idx[r],:]  (overwrites latents in-place)
//     + vq partial sums  sum((q - l)^2)
// ---------------------------------------------------------------------------
__global__ __launch_bounds__(256) void k_quant(const float* __restrict__ protos,
                                               const int* __restrict__ idx,
                                               float* __restrict__ out,
                                               float* __restrict__ vq_acc) {
    const int tid = threadIdx.x;
    const int r = blockIdx.x * 2 + (tid >> 7);
    const int c = (tid & 127) * 4;
    const int p = idx[r];
    float4 q = *(const float4*)(protos + (size_t)p * D_DIM + c);
    float4 l = *(const float4*)(out + (size_t)r * D_DIM + c);
    float dx = q.x - l.x, dy = q.y - l.y, dz = q.z - l.z, dw = q.w - l.w;
    float s = dx * dx + dy * dy + dz * dz + dw * dw;
    *(float4*)(out + (size_t)r * D_DIM + c) = q;
#pragma unroll
    for (int m = 1; m < 64; m <<= 1) s += __shfl_xor(s, m);
    __shared__ float red[4];
    if ((tid & 63) == 0) red[tid >> 6] = s;
    __syncthreads();
    if (tid == 0) atomicAdd(vq_acc, red[0] + red[1] + red[2] + red[3]);
}

// ---------------------------------------------------------------------------
// K6: finalize scalars.
// ---------------------------------------------------------------------------
__global__ __launch_bounds__(256) void k_final(const float* __restrict__ soft_acc,
                                               const float* __restrict__ scal,
                                               float* __restrict__ out) {
    const int tid = threadIdx.x;
    __shared__ float red[256];
    float vals[8];
    float s = 0.f;
#pragma unroll
    for (int i = 0; i < 8; ++i) {
        float v = soft_acc[tid * 8 + i] * (1.0f / B_N) + 1e-6f;
        vals[i] = v;
        s += v;
    }
    red[tid] = s;
    __syncthreads();
    for (int off = 128; off > 0; off >>= 1) {
        if (tid < off) red[tid] += red[tid + off];
        __syncthreads();
    }
    float norm = red[0];
    __syncthreads();
    float e = 0.f;
#pragma unroll
    for (int i = 0; i < 8; ++i) {
        float p = vals[i] / norm;
        e -= p * __logf(p);
    }
    red[tid] = e;
    __syncthreads();
    for (int off = 128; off > 0; off >>= 1) {
        if (tid < off) red[tid] += red[tid + off];
        __syncthreads();
    }
    if (tid == 0) {
        float ent = red[0];
        float div = scal[0] * (1.0f / B_N);
        float vq = scal[1] * (1.0f / ((float)B_N * (float)D_DIM));
        float vq_loss = 1.25f * vq + 0.1f * ent;  // commitment*0.25 + embedding + ent_w*ent
        float total = 0.01f * div + vq_loss;
        out[(size_t)B_N * D_DIM] = total;
        out[(size_t)B_N * D_DIM + 1] = div;
    }
}

// ---------------------------------------------------------------------------
extern "C" void kernel_launch(void* const* d_in, const int* in_sizes, int n_in,
                              void* d_out, int out_size, void* d_ws, size_t ws_size,
                              hipStream_t stream) {
    const float* x = (const float*)d_in[0];
    const float* W0 = (const float*)d_in[1];
    const float* b0 = (const float*)d_in[2];
    const float* W1 = (const float*)d_in[3];
    const float* b1 = (const float*)d_in[4];
    const float* Wmu = (const float*)d_in[5];
    const float* bmu = (const float*)d_in[6];
    const float* Wvar = (const float*)d_in[7];
    const float* bvar = (const float*)d_in[8];
    const float* protos = (const float*)d_in[9];
    const float* eps = (const float*)d_in[10];
    float* out = (float*)d_out;

    float* ws = (float*)d_ws;
    float* h1 = ws;                                     // B*64
    float* h2 = h1 + (size_t)B_N * HID;                 // B*512
    float* pnorm = h2 + (size_t)B_N * D_DIM;            // 2048
    float* soft = pnorm + P_N;                          // 2048
    float* scal = soft + P_N;                           // 2  (div_sum, vq_sum)
    int* idx = (int*)(scal + 2);                        // B ints

    // zero accumulators (soft + scal are contiguous)
    hipMemsetAsync(soft, 0, (P_N + 2) * sizeof(float), stream);

    k_enc1<<<B_N / 128, 256, 0, stream>>>(x, W0, b0, h1);
    dim3 g2(B_N / 128, D_DIM / 128);
    k_enc2<<<g2, 256, 0, stream>>>(h1, W1, b1, h2);
    dim3 g3(B_N / 128, D_DIM / 64);
    k_muvar<<<g3, 256, 0, stream>>>(h2, Wmu, bmu, Wvar, bvar, eps, out, scal);
    k_pnorm<<<P_N / 4, 256, 0, stream>>>(protos, pnorm);
    k_vq<<<B_N / 64, 256, 0, stream>>>(out, protos, pnorm, idx, soft);
    k_quant<<<B_N / 2, 256, 0, stream>>>(protos, idx, out, scal + 1);
    k_final<<<1, 256, 0, stream>>>(soft, scal, out);
}

// Round 2
// 1138.551 us; speedup vs baseline: 2.9315x; 2.9315x over previous
//
#include <hip/hip_runtime.h>
#include <math.h>

#define B_N 32768
#define IN_DIM 1024
#define HID 64
#define D_DIM 512
#define P_N 2048

typedef __attribute__((ext_vector_type(8))) short s16x8;
typedef __attribute__((ext_vector_type(4))) short s16x4;
typedef __attribute__((ext_vector_type(4))) float f32x4;

__device__ __forceinline__ unsigned short f2bf(float f) {
    unsigned u = __float_as_uint(f);
    return (unsigned short)((u + 0x7fffu + ((u >> 16) & 1u)) >> 16);
}

// ---------------------------------------------------------------------------
// K1: h1 = relu(x @ W0^T + b0)   [B,1024] -> [B,64]   (fp32 VALU)
// ---------------------------------------------------------------------------
__global__ __launch_bounds__(256) void k_enc1(const float* __restrict__ x,
                                              const float* __restrict__ W0,
                                              const float* __restrict__ b0,
                                              float* __restrict__ h1) {
    __shared__ float As[128][33];
    __shared__ float Ws[64][33];
    const int tid = threadIdx.x;
    const int tx = tid & 15, ty = tid >> 4;
    const int bm = blockIdx.x * 128;

    float acc[8][4] = {};
    for (int k0 = 0; k0 < IN_DIM; k0 += 32) {
#pragma unroll
        for (int i = 0; i < 4; ++i) {
            int li = tid + i * 256;
            int r = li >> 3, c = (li & 7) << 2;
            float4 v = *(const float4*)(x + (size_t)(bm + r) * IN_DIM + k0 + c);
            As[r][c] = v.x; As[r][c + 1] = v.y; As[r][c + 2] = v.z; As[r][c + 3] = v.w;
        }
#pragma unroll
        for (int i = 0; i < 2; ++i) {
            int li = tid + i * 256;
            int r = li >> 3, c = (li & 7) << 2;
            float4 v = *(const float4*)(W0 + (size_t)r * IN_DIM + k0 + c);
            Ws[r][c] = v.x; Ws[r][c + 1] = v.y; Ws[r][c + 2] = v.z; Ws[r][c + 3] = v.w;
        }
        __syncthreads();
#pragma unroll 16
        for (int kk = 0; kk < 32; ++kk) {
            float a[8], w[4];
#pragma unroll
            for (int i = 0; i < 8; ++i) a[i] = As[ty * 8 + i][kk];
#pragma unroll
            for (int j = 0; j < 4; ++j) w[j] = Ws[tx * 4 + j][kk];
#pragma unroll
            for (int i = 0; i < 8; ++i)
#pragma unroll
                for (int j = 0; j < 4; ++j)
                    acc[i][j] = fmaf(a[i], w[j], acc[i][j]);
        }
        __syncthreads();
    }
#pragma unroll
    for (int i = 0; i < 8; ++i) {
        int r = bm + ty * 8 + i;
        float4 o;
        float b;
        b = b0[tx * 4 + 0]; o.x = fmaxf(acc[i][0] + b, 0.f);
        b = b0[tx * 4 + 1]; o.y = fmaxf(acc[i][1] + b, 0.f);
        b = b0[tx * 4 + 2]; o.z = fmaxf(acc[i][2] + b, 0.f);
        b = b0[tx * 4 + 3]; o.w = fmaxf(acc[i][3] + b, 0.f);
        *(float4*)(h1 + (size_t)r * HID + tx * 4) = o;
    }
}

// ---------------------------------------------------------------------------
// K2: h2 = relu(h1 @ W1^T + b1)   [B,64] -> [B,512]  output bf16
// ---------------------------------------------------------------------------
__global__ __launch_bounds__(256) void k_enc2(const float* __restrict__ h1,
                                              const float* __restrict__ W1,
                                              const float* __restrict__ b1,
                                              unsigned short* __restrict__ h2b) {
    __shared__ float As[128][65];
    __shared__ float Ws[128][65];
    const int tid = threadIdx.x;
    const int tx = tid & 15, ty = tid >> 4;
    const int bm = blockIdx.x * 128;
    const int bn = blockIdx.y * 128;

#pragma unroll
    for (int i = 0; i < 8; ++i) {
        int li = tid + i * 256;
        int r = li >> 4, c = (li & 15) << 2;
        float4 v = *(const float4*)(h1 + (size_t)(bm + r) * HID + c);
        As[r][c] = v.x; As[r][c + 1] = v.y; As[r][c + 2] = v.z; As[r][c + 3] = v.w;
    }
#pragma unroll
    for (int i = 0; i < 8; ++i) {
        int li = tid + i * 256;
        int r = li >> 4, c = (li & 15) << 2;
        float4 v = *(const float4*)(W1 + (size_t)(bn + r) * HID + c);
        Ws[r][c] = v.x; Ws[r][c + 1] = v.y; Ws[r][c + 2] = v.z; Ws[r][c + 3] = v.w;
    }
    __syncthreads();

    float acc[8][8] = {};
#pragma unroll 16
    for (int kk = 0; kk < 64; ++kk) {
        float a[8], w[8];
#pragma unroll
        for (int i = 0; i < 8; ++i) a[i] = As[ty * 8 + i][kk];
#pragma unroll
        for (int j = 0; j < 4; ++j) {
            w[j] = Ws[tx * 4 + j][kk];
            w[4 + j] = Ws[64 + tx * 4 + j][kk];
        }
#pragma unroll
        for (int i = 0; i < 8; ++i)
#pragma unroll
            for (int j = 0; j < 8; ++j)
                acc[i][j] = fmaf(a[i], w[j], acc[i][j]);
    }

#pragma unroll
    for (int i = 0; i < 8; ++i) {
        int r = bm + ty * 8 + i;
        s16x4 o1, o2;
        o1[0] = (short)f2bf(fmaxf(acc[i][0] + b1[bn + tx * 4 + 0], 0.f));
        o1[1] = (short)f2bf(fmaxf(acc[i][1] + b1[bn + tx * 4 + 1], 0.f));
        o1[2] = (short)f2bf(fmaxf(acc[i][2] + b1[bn + tx * 4 + 2], 0.f));
        o1[3] = (short)f2bf(fmaxf(acc[i][3] + b1[bn + tx * 4 + 3], 0.f));
        o2[0] = (short)f2bf(fmaxf(acc[i][4] + b1[bn + 64 + tx * 4 + 0], 0.f));
        o2[1] = (short)f2bf(fmaxf(acc[i][5] + b1[bn + 64 + tx * 4 + 1], 0.f));
        o2[2] = (short)f2bf(fmaxf(acc[i][6] + b1[bn + 64 + tx * 4 + 2], 0.f));
        o2[3] = (short)f2bf(fmaxf(acc[i][7] + b1[bn + 64 + tx * 4 + 3], 0.f));
        *(s16x4*)(h2b + (size_t)r * D_DIM + bn + tx * 4) = o1;
        *(s16x4*)(h2b + (size_t)r * D_DIM + bn + 64 + tx * 4) = o2;
    }
}

// ---------------------------------------------------------------------------
// Pack fp32 [nrows, 512] row-major -> bf16 MFMA-B-fragment-major:
// elem (row,k) -> dst[ ((P16*16 + K32)*64 + lane)*8 + j ]
//   P16=row>>4, K32=k>>5, lane=(row&15)|(((k>>3)&3)<<4), j=k&7
// One thread per (row, 8k-group).
// ---------------------------------------------------------------------------
__global__ __launch_bounds__(256) void k_pack(const float* __restrict__ src,
                                              unsigned short* __restrict__ dst,
                                              int nrows) {
    int gid = blockIdx.x * 256 + threadIdx.x;
    if (gid >= nrows * 64) return;
    int row = gid >> 6, k8 = gid & 63;
    int K32 = k8 >> 2, lsub = k8 & 3;
    int lane = (row & 15) | (lsub << 4);
    int P16 = row >> 4;
    const float* s = src + (size_t)row * D_DIM + k8 * 8;
    float4 x = *(const float4*)s;
    float4 y = *(const float4*)(s + 4);
    s16x8 o;
    o[0] = (short)f2bf(x.x); o[1] = (short)f2bf(x.y);
    o[2] = (short)f2bf(x.z); o[3] = (short)f2bf(x.w);
    o[4] = (short)f2bf(y.x); o[5] = (short)f2bf(y.y);
    o[6] = (short)f2bf(y.z); o[7] = (short)f2bf(y.w);
    ((s16x8*)dst)[((size_t)P16 * 16 + K32) * 64 + lane] = o;
}

// ---------------------------------------------------------------------------
// K3 (MFMA): mu/logvar GEMMs + reparameterize + KL partial sums.
// Block: 64 rows, 4 waves; wave covers 32 d-cols x {mu,var}; dt loop x4.
// ---------------------------------------------------------------------------
__global__ __launch_bounds__(256, 2) void k_muvar(const unsigned short* __restrict__ h2b,
                                                  const unsigned short* __restrict__ wmP,
                                                  const unsigned short* __restrict__ wvP,
                                                  const float* __restrict__ bmu,
                                                  const float* __restrict__ bvar,
                                                  const float* __restrict__ eps,
                                                  float* __restrict__ lat,
                                                  float* __restrict__ div_acc) {
    __shared__ s16x8 Hs[4096];  // 64 rows x 512 bf16, XOR-swizzled, 64 KB
    __shared__ float red[4];
    const int tid = threadIdx.x;
    const int l = tid & 63, wid = tid >> 6;
    const int bm = blockIdx.x * 64;

    {   // stage h2 (bf16) -> swizzled LDS
        const int row = tid >> 2, sub = tid & 3;
        const s16x8* src = (const s16x8*)(h2b + (size_t)(bm + row) * D_DIM) + sub * 16;
        const int rb = row * 1024, sw = (row & 7) << 4;
#pragma unroll
        for (int it = 0; it < 16; ++it) {
            s16x8 v = src[it];
            int kbyte = (sub * 128 + it * 8) * 2;
            Hs[(rb + (kbyte ^ sw)) >> 4] = v;
        }
    }
    __syncthreads();

    const s16x8* wm8 = (const s16x8*)wmP;
    const s16x8* wv8 = (const s16x8*)wvP;
    const int klane = (l >> 4) << 4;
    const int sw = (l & 7) << 4;
    int aoff[4];
#pragma unroll
    for (int m = 0; m < 4; ++m) aoff[m] = (m * 16 + (l & 15)) * 1024;

    float kl = 0.f;
    for (int dt = 0; dt < 4; ++dt) {
        const int dbase = dt * 128 + wid * 32;
        const int P16 = dbase >> 4;
        f32x4 aM[4][2], aV[4][2];
#pragma unroll
        for (int m = 0; m < 4; ++m)
#pragma unroll
            for (int f = 0; f < 2; ++f) { aM[m][f] = (f32x4)0.f; aV[m][f] = (f32x4)0.f; }

#pragma unroll
        for (int K32 = 0; K32 < 16; ++K32) {
            s16x8 bM[2], bV[2];
#pragma unroll
            for (int f = 0; f < 2; ++f) {
                bM[f] = wm8[((size_t)(P16 + f) * 16 + K32) * 64 + l];
                bV[f] = wv8[((size_t)(P16 + f) * 16 + K32) * 64 + l];
            }
            const int kb = ((K32 << 6) + klane) ^ sw;
            s16x8 a[4];
#pragma unroll
            for (int m = 0; m < 4; ++m) a[m] = Hs[(aoff[m] + kb) >> 4];
#pragma unroll
            for (int m = 0; m < 4; ++m)
#pragma unroll
                for (int f = 0; f < 2; ++f) {
                    aM[m][f] = __builtin_amdgcn_mfma_f32_16x16x32_bf16(a[m], bM[f], aM[m][f], 0, 0, 0);
                    aV[m][f] = __builtin_amdgcn_mfma_f32_16x16x32_bf16(a[m], bV[f], aV[m][f], 0, 0, 0);
                }
        }
        // epilogue: bias, reparam, KL
#pragma unroll
        for (int m = 0; m < 4; ++m)
#pragma unroll
            for (int f = 0; f < 2; ++f) {
                const int d = dbase + f * 16 + (l & 15);
                const float bmv = bmu[d], bvv = bvar[d];
#pragma unroll
                for (int j = 0; j < 4; ++j) {
                    const int row = bm + m * 16 + (l >> 4) * 4 + j;
                    float mu = aM[m][f][j] + bmv;
                    float lv = aV[m][f][j] + bvv;
                    float el = __expf(lv);
                    float la = fmaf(eps[(size_t)row * D_DIM + d], __expf(0.5f * lv), mu);
                    lat[(size_t)row * D_DIM + d] = la;
                    kl += mu * mu + el - lv - 1.f;
                }
            }
    }
    kl *= 0.5f;
#pragma unroll
    for (int m = 1; m < 64; m <<= 1) kl += __shfl_xor(kl, m);
    if (l == 0) red[wid] = kl;
    __syncthreads();
    if (tid == 0) atomicAdd(div_acc, red[0] + red[1] + red[2] + red[3]);
}

// ---------------------------------------------------------------------------
// K4a: pnorm[p] = sum_d protos[p,d]^2
// ---------------------------------------------------------------------------
__global__ __launch_bounds__(256) void k_pnorm(const float* __restrict__ protos,
                                               float* __restrict__ pnorm) {
    const int p = blockIdx.x * 4 + (threadIdx.x >> 6);
    const int lane = threadIdx.x & 63;
    const float* row = protos + (size_t)p * D_DIM;
    float4 v1 = *(const float4*)(row + lane * 8);
    float4 v2 = *(const float4*)(row + lane * 8 + 4);
    float s = v1.x * v1.x + v1.y * v1.y + v1.z * v1.z + v1.w * v1.w +
              v2.x * v2.x + v2.y * v2.y + v2.z * v2.z + v2.w * v2.w;
#pragma unroll
    for (int m = 1; m < 64; m <<= 1) s += __shfl_xor(s, m);
    if (lane == 0) pnorm[p] = s;
}

// ---------------------------------------------------------------------------
// K4 (MFMA): per-row G[p]=2*l.p-|p|^2 over P=2048.
// sweep0: per-lane sum(exp)+argmax, cross-lane+cross-wave combine -> idx, 1/S
// sweep1: recompute, accumulate exp(g)/S into soft_acc.
// Block = 64 rows (latents in swizzled LDS), 4 waves x 64 protos per tile.
// No barriers in the K-loop; B-frags are coalesced 1KB/wave loads from ppack.
// ---------------------------------------------------------------------------
__device__ __forceinline__ void vq_tile(const s16x8* __restrict__ Ls,
                                        const s16x8* __restrict__ bpk,
                                        int P16, int l, int klane, int sw,
                                        const int aoff[4], f32x4 acc[4][4]) {
#pragma unroll
    for (int K32 = 0; K32 < 16; ++K32) {
        s16x8 b[4];
#pragma unroll
        for (int pf = 0; pf < 4; ++pf) b[pf] = bpk[((size_t)(P16 + pf) * 16 + K32) * 64 + l];
        const int kb = ((K32 << 6) + klane) ^ sw;
        s16x8 a[4];
#pragma unroll
        for (int m = 0; m < 4; ++m) a[m] = Ls[(aoff[m] + kb) >> 4];
#pragma unroll
        for (int m = 0; m < 4; ++m)
#pragma unroll
            for (int pf = 0; pf < 4; ++pf)
                acc[m][pf] = __builtin_amdgcn_mfma_f32_16x16x32_bf16(a[m], b[pf], acc[m][pf], 0, 0, 0);
    }
}

__global__ __launch_bounds__(256, 2) void k_vq(const float* __restrict__ lat,
                                               const unsigned short* __restrict__ ppack,
                                               const float* __restrict__ pnorm,
                                               int* __restrict__ idxOut,
                                               float* __restrict__ soft_acc) {
    __shared__ s16x8 Ls[4096];  // 64 KB
    __shared__ float rS[4][64];
    __shared__ float rM[4][64];
    __shared__ int rI[4][64];
    __shared__ float invS[64];
    const int tid = threadIdx.x;
    const int l = tid & 63, wid = tid >> 6;
    const int bm = blockIdx.x * 64;

    {   // stage latents fp32 -> bf16 swizzled LDS
        const int row = tid >> 2, sub = tid & 3;
        const float* src = lat + (size_t)(bm + row) * D_DIM + sub * 128;
        const int rb = row * 1024, sw0 = (row & 7) << 4;
#pragma unroll
        for (int it = 0; it < 16; ++it) {
            float4 a = *(const float4*)(src + it * 8);
            float4 b = *(const float4*)(src + it * 8 + 4);
            s16x8 o;
            o[0] = (short)f2bf(a.x); o[1] = (short)f2bf(a.y);
            o[2] = (short)f2bf(a.z); o[3] = (short)f2bf(a.w);
            o[4] = (short)f2bf(b.x); o[5] = (short)f2bf(b.y);
            o[6] = (short)f2bf(b.z); o[7] = (short)f2bf(b.w);
            int kbyte = (sub * 128 + it * 8) * 2;
            Ls[(rb + (kbyte ^ sw0)) >> 4] = o;
        }
    }
    __syncthreads();

    const s16x8* ppk = (const s16x8*)ppack;
    const int klane = (l >> 4) << 4;
    const int sw = (l & 7) << 4;
    int aoff[4];
#pragma unroll
    for (int m = 0; m < 4; ++m) aoff[m] = (m * 16 + (l & 15)) * 1024;

    float s_sum[4][4], mv[4][4];
    int mi[4][4];
#pragma unroll
    for (int m = 0; m < 4; ++m)
#pragma unroll
        for (int j = 0; j < 4; ++j) { s_sum[m][j] = 0.f; mv[m][j] = -1e30f; mi[m][j] = 0x7fffffff; }

    // ---------------- sweep 0: sumexp + argmax ----------------
    for (int t = 0; t < 8; ++t) {
        const int pbase = t * 256 + wid * 64;
        const int P16 = pbase >> 4;
        float pn[4];
#pragma unroll
        for (int pf = 0; pf < 4; ++pf) pn[pf] = pnorm[pbase + pf * 16 + (l & 15)];
        f32x4 acc[4][4];
#pragma unroll
        for (int m = 0; m < 4; ++m)
#pragma unroll
            for (int pf = 0; pf < 4; ++pf) acc[m][pf] = (f32x4)0.f;
        vq_tile(Ls, ppk, P16, l, klane, sw, aoff, acc);
#pragma unroll
        for (int m = 0; m < 4; ++m)
#pragma unroll
            for (int pf = 0; pf < 4; ++pf) {
                const int p = pbase + pf * 16 + (l & 15);
#pragma unroll
                for (int j = 0; j < 4; ++j) {
                    float g = 2.f * acc[m][pf][j] - pn[pf];
                    s_sum[m][j] += __expf(g);
                    if (g > mv[m][j] || (g == mv[m][j] && p < mi[m][j])) { mv[m][j] = g; mi[m][j] = p; }
                }
            }
    }
    // cross-lane (16-group) then cross-wave combine
#pragma unroll
    for (int m = 0; m < 4; ++m)
#pragma unroll
        for (int j = 0; j < 4; ++j) {
            float s = s_sum[m][j];
            float v = mv[m][j];
            int i = mi[m][j];
#pragma unroll
            for (int d = 1; d < 16; d <<= 1) {
                s += __shfl_xor(s, d);
                float ov = __shfl_xor(v, d);
                int oi = __shfl_xor(i, d);
                if (ov > v || (ov == v && oi < i)) { v = ov; i = oi; }
            }
            if ((l & 15) == 0) {
                int row = m * 16 + (l >> 4) * 4 + j;
                rS[wid][row] = s; rM[wid][row] = v; rI[wid][row] = i;
            }
        }
    __syncthreads();
    if (tid < 64) {
        float s = 0.f, v = -1e30f;
        int bi = 0x7fffffff;
#pragma unroll
        for (int w = 0; w < 4; ++w) {
            s += rS[w][tid];
            float ov = rM[w][tid];
            int oi = rI[w][tid];
            if (ov > v || (ov == v && oi < bi)) { v = ov; bi = oi; }
        }
        idxOut[bm + tid] = bi;
        invS[tid] = 1.f / s;
    }
    __syncthreads();
    float is[4][4];
#pragma unroll
    for (int m = 0; m < 4; ++m)
#pragma unroll
        for (int j = 0; j < 4; ++j) is[m][j] = invS[m * 16 + (l >> 4) * 4 + j];

    // ---------------- sweep 1: soft assignment accumulation ----------------
    for (int t = 0; t < 8; ++t) {
        const int pbase = t * 256 + wid * 64;
        const int P16 = pbase >> 4;
        float pn[4];
#pragma unroll
        for (int pf = 0; pf < 4; ++pf) pn[pf] = pnorm[pbase + pf * 16 + (l & 15)];
        f32x4 acc[4][4];
#pragma unroll
        for (int m = 0; m < 4; ++m)
#pragma unroll
            for (int pf = 0; pf < 4; ++pf) acc[m][pf] = (f32x4)0.f;
        vq_tile(Ls, ppk, P16, l, klane, sw, aoff, acc);
        float c[4] = {0.f, 0.f, 0.f, 0.f};
#pragma unroll
        for (int m = 0; m < 4; ++m)
#pragma unroll
            for (int pf = 0; pf < 4; ++pf)
#pragma unroll
                for (int j = 0; j < 4; ++j) {
                    float g = 2.f * acc[m][pf][j] - pn[pf];
                    c[pf] += __expf(g) * is[m][j];
                }
#pragma unroll
        for (int pf = 0; pf < 4; ++pf) {
            c[pf] += __shfl_xor(c[pf], 16);
            c[pf] += __shfl_xor(c[pf], 32);
        }
        if (l < 16) {
#pragma unroll
            for (int pf = 0; pf < 4; ++pf) atomicAdd(&soft_acc[pbase + pf * 16 + l], c[pf]);
        }
    }
}

// ---------------------------------------------------------------------------
// K5: out[r,:] = protos[idx[r],:]  (overwrites latents) + vq partial sums
// ---------------------------------------------------------------------------
__global__ __launch_bounds__(256) void k_quant(const float* __restrict__ protos,
                                               const int* __restrict__ idx,
                                               float* __restrict__ out,
                                               float* __restrict__ vq_acc) {
    const int tid = threadIdx.x;
    const int r = blockIdx.x * 2 + (tid >> 7);
    const int c = (tid & 127) * 4;
    const int p = idx[r];
    float4 q = *(const float4*)(protos + (size_t)p * D_DIM + c);
    float4 lv = *(const float4*)(out + (size_t)r * D_DIM + c);
    float dx = q.x - lv.x, dy = q.y - lv.y, dz = q.z - lv.z, dw = q.w - lv.w;
    float s = dx * dx + dy * dy + dz * dz + dw * dw;
    *(float4*)(out + (size_t)r * D_DIM + c) = q;
#pragma unroll
    for (int m = 1; m < 64; m <<= 1) s += __shfl_xor(s, m);
    __shared__ float red[4];
    if ((tid & 63) == 0) red[tid >> 6] = s;
    __syncthreads();
    if (tid == 0) atomicAdd(vq_acc, red[0] + red[1] + red[2] + red[3]);
}

// ---------------------------------------------------------------------------
// K6: finalize scalars.
// ---------------------------------------------------------------------------
__global__ __launch_bounds__(256) void k_final(const float* __restrict__ soft_acc,
                                               const float* __restrict__ scal,
                                               float* __restrict__ out) {
    const int tid = threadIdx.x;
    __shared__ float red[256];
    float vals[8];
    float s = 0.f;
#pragma unroll
    for (int i = 0; i < 8; ++i) {
        float v = soft_acc[tid * 8 + i] * (1.0f / B_N) + 1e-6f;
        vals[i] = v;
        s += v;
    }
    red[tid] = s;
    __syncthreads();
    for (int off = 128; off > 0; off >>= 1) {
        if (tid < off) red[tid] += red[tid + off];
        __syncthreads();
    }
    float norm = red[0];
    __syncthreads();
    float e = 0.f;
#pragma unroll
    for (int i = 0; i < 8; ++i) {
        float p = vals[i] / norm;
        e -= p * __logf(p);
    }
    red[tid] = e;
    __syncthreads();
    for (int off = 128; off > 0; off >>= 1) {
        if (tid < off) red[tid] += red[tid + off];
        __syncthreads();
    }
    if (tid == 0) {
        float ent = red[0];
        float div = scal[0] * (1.0f / B_N);
        float vq = scal[1] * (1.0f / ((float)B_N * (float)D_DIM));
        float vq_loss = 1.25f * vq + 0.1f * ent;
        float total = 0.01f * div + vq_loss;
        out[(size_t)B_N * D_DIM] = total;
        out[(size_t)B_N * D_DIM + 1] = div;
    }
}

// ---------------------------------------------------------------------------
extern "C" void kernel_launch(void* const* d_in, const int* in_sizes, int n_in,
                              void* d_out, int out_size, void* d_ws, size_t ws_size,
                              hipStream_t stream) {
    const float* x = (const float*)d_in[0];
    const float* W0 = (const float*)d_in[1];
    const float* b0 = (const float*)d_in[2];
    const float* W1 = (const float*)d_in[3];
    const float* b1 = (const float*)d_in[4];
    const float* Wmu = (const float*)d_in[5];
    const float* bmu = (const float*)d_in[6];
    const float* Wvar = (const float*)d_in[7];
    const float* bvar = (const float*)d_in[8];
    const float* protos = (const float*)d_in[9];
    const float* eps = (const float*)d_in[10];
    float* out = (float*)d_out;

    float* ws = (float*)d_ws;
    float* h1 = ws;                                                   // B*64 f32
    unsigned short* h2b = (unsigned short*)(h1 + (size_t)B_N * HID);  // B*512 bf16
    unsigned short* ppack = h2b + (size_t)B_N * D_DIM;                // 2048*512 bf16
    unsigned short* wmpack = ppack + (size_t)P_N * D_DIM;             // 512*512 bf16
    unsigned short* wvpack = wmpack + (size_t)D_DIM * D_DIM;          // 512*512 bf16
    float* pnorm = (float*)(wvpack + (size_t)D_DIM * D_DIM);          // 2048 f32
    float* soft = pnorm + P_N;                                        // 2048 f32
    float* scal = soft + P_N;                                         // 2
    int* idx = (int*)(scal + 2);                                      // B int

    hipMemsetAsync(soft, 0, (P_N + 2) * sizeof(float), stream);

    k_enc1<<<B_N / 128, 256, 0, stream>>>(x, W0, b0, h1);
    dim3 g2(B_N / 128, D_DIM / 128);
    k_enc2<<<g2, 256, 0, stream>>>(h1, W1, b1, h2b);
    k_pack<<<P_N * 64 / 256, 256, 0, stream>>>(protos, ppack, P_N);
    k_pack<<<D_DIM * 64 / 256, 256, 0, stream>>>(Wmu, wmpack, D_DIM);
    k_pack<<<D_DIM * 64 / 256, 256, 0, stream>>>(Wvar, wvpack, D_DIM);
    k_pnorm<<<P_N / 4, 256, 0, stream>>>(protos, pnorm);
    k_muvar<<<B_N / 64, 256, 0, stream>>>(h2b, wmpack, wvpack, bmu, bvar, eps, out, scal);
    k_vq<<<B_N / 64, 256, 0, stream>>>(out, ppack, pnorm, idx, soft);
    k_quant<<<B_N / 2, 256, 0, stream>>>(protos, idx, out, scal + 1);
    k_final<<<1, 256, 0, stream>>>(soft, scal, out);
}

// Round 4
// 1133.511 us; speedup vs baseline: 2.9445x; 1.0044x over previous
//
#include <hip/hip_runtime.h>
#include <math.h>

#define B_N 32768
#define IN_DIM 1024
#define HID 64
#define D_DIM 512
#define P_N 2048

typedef __attribute__((ext_vector_type(8))) short s16x8;
typedef __attribute__((ext_vector_type(4))) short s16x4;
typedef __attribute__((ext_vector_type(4))) float f32x4;

__device__ __forceinline__ unsigned short f2bf(float f) {
    unsigned u = __float_as_uint(f);
    return (unsigned short)((u + 0x7fffu + ((u >> 16) & 1u)) >> 16);
}

// ---------------------------------------------------------------------------
// Pack fp32 [nrows, ncols] row-major -> bf16 MFMA-B-fragment-major.
// frag unit: ((P16*nk32 + K32)*64 + lane) * 8 elems; lane=(row&15)|((k8&3)<<4)
// ---------------------------------------------------------------------------
__global__ __launch_bounds__(256) void k_pack(const float* __restrict__ src,
                                              unsigned short* __restrict__ dst,
                                              int nrows, int nk8) {
    int gid = blockIdx.x * 256 + threadIdx.x;
    if (gid >= nrows * nk8) return;
    int row = gid / nk8, k8 = gid % nk8;
    int K32 = k8 >> 2;
    int lane = (row & 15) | ((k8 & 3) << 4);
    int P16 = row >> 4;
    int nk32 = nk8 >> 2;
    const float* s = src + (size_t)row * (nk8 * 8) + k8 * 8;
    float4 x = *(const float4*)s;
    float4 y = *(const float4*)(s + 4);
    s16x8 o;
    o[0] = (short)f2bf(x.x); o[1] = (short)f2bf(x.y);
    o[2] = (short)f2bf(x.z); o[3] = (short)f2bf(x.w);
    o[4] = (short)f2bf(y.x); o[5] = (short)f2bf(y.y);
    o[6] = (short)f2bf(y.z); o[7] = (short)f2bf(y.w);
    ((s16x8*)dst)[((size_t)P16 * nk32 + K32) * 64 + lane] = o;
}

// ---------------------------------------------------------------------------
// K1 (MFMA): h1 = relu(x @ W0^T + b0)  [B,1024] -> [B,64] bf16 out
// BM=128 (4 waves x 32 rows, each wave ALL 64 cols), BK=128.
// ---------------------------------------------------------------------------
__global__ __launch_bounds__(256, 4) void k_enc1(const float* __restrict__ x,
                                                 const unsigned short* __restrict__ w0p,
                                                 const float* __restrict__ b0,
                                                 unsigned short* __restrict__ h1b) {
    __shared__ s16x8 As[2048];  // 128 rows x 128 bf16, 32 KB
    const int tid = threadIdx.x;
    const int l = tid & 63, wid = tid >> 6;
    const int bm = blockIdx.x * 128;
    const s16x8* w0p8 = (const s16x8*)w0p;

    const int srow = tid >> 1, ssub = tid & 1;
    const int srb = srow * 256, ssw = (srow & 7) << 4;

    const int klane = (l >> 4) << 4;
    const int sw = (l & 7) << 4;
    int aoff[2];
#pragma unroll
    for (int m = 0; m < 2; ++m) aoff[m] = (wid * 32 + m * 16 + (l & 15)) * 256;

    f32x4 acc[2][4];
#pragma unroll
    for (int m = 0; m < 2; ++m)
#pragma unroll
        for (int pf = 0; pf < 4; ++pf) acc[m][pf] = (f32x4)0.f;

    for (int kt = 0; kt < 8; ++kt) {
        const float* src = x + (size_t)(bm + srow) * IN_DIM + kt * 128 + ssub * 64;
#pragma unroll
        for (int it = 0; it < 8; ++it) {
            float4 a = *(const float4*)(src + it * 8);
            float4 b = *(const float4*)(src + it * 8 + 4);
            s16x8 o;
            o[0] = (short)f2bf(a.x); o[1] = (short)f2bf(a.y);
            o[2] = (short)f2bf(a.z); o[3] = (short)f2bf(a.w);
            o[4] = (short)f2bf(b.x); o[5] = (short)f2bf(b.y);
            o[6] = (short)f2bf(b.z); o[7] = (short)f2bf(b.w);
            int kbyte = ssub * 128 + it * 16;
            As[(srb + (kbyte ^ ssw)) >> 4] = o;
        }
        __syncthreads();
#pragma unroll
        for (int K32 = 0; K32 < 4; ++K32) {
            const int Kg = kt * 4 + K32;
            s16x8 b[4];
#pragma unroll
            for (int pf = 0; pf < 4; ++pf) b[pf] = w0p8[((size_t)pf * 32 + Kg) * 64 + l];
            const int kb = (K32 * 64 + klane) ^ sw;
            s16x8 a[2];
#pragma unroll
            for (int m = 0; m < 2; ++m) a[m] = As[(aoff[m] + kb) >> 4];
#pragma unroll
            for (int m = 0; m < 2; ++m)
#pragma unroll
                for (int pf = 0; pf < 4; ++pf)
                    acc[m][pf] = __builtin_amdgcn_mfma_f32_16x16x32_bf16(a[m], b[pf], acc[m][pf], 0, 0, 0);
        }
        __syncthreads();
    }
#pragma unroll
    for (int m = 0; m < 2; ++m)
#pragma unroll
        for (int pf = 0; pf < 4; ++pf) {
            const int c = pf * 16 + (l & 15);
            const float bb = b0[c];
#pragma unroll
            for (int j = 0; j < 4; ++j) {
                const int r = bm + wid * 32 + m * 16 + (l >> 4) * 4 + j;
                h1b[(size_t)r * HID + c] = f2bf(fmaxf(acc[m][pf][j] + bb, 0.f));
            }
        }
}

// ---------------------------------------------------------------------------
// K2 (MFMA): h2 = relu(h1 @ W1^T + b1)  [B,64] -> [B,512] bf16
// BM=64: 4 waves partition ROWS (16 each); every wave computes ALL 512 cols
// via 4 col-quarter passes (acc[8] per pass).  [R3 bug fix: was diagonal-only]
// ---------------------------------------------------------------------------
__global__ __launch_bounds__(256, 4) void k_enc2(const unsigned short* __restrict__ h1b,
                                                 const unsigned short* __restrict__ w1p,
                                                 const float* __restrict__ b1,
                                                 unsigned short* __restrict__ h2b) {
    __shared__ s16x8 As[512];  // 64 rows x 64 bf16, 8 KB
    const int tid = threadIdx.x;
    const int l = tid & 63, wid = tid >> 6;
    const int bm = blockIdx.x * 64;
    const s16x8* w1p8 = (const s16x8*)w1p;

#pragma unroll
    for (int it = 0; it < 2; ++it) {
        int g = tid * 2 + it;
        int row = g >> 3, k8 = g & 7;
        s16x8 v = ((const s16x8*)(h1b + (size_t)(bm + row) * HID))[k8];
        As[(row * 128 + ((k8 * 16) ^ ((row & 7) << 4))) >> 4] = v;
    }
    __syncthreads();

    const int arow = wid * 16 + (l & 15);
    const int sw = (l & 7) << 4;
    const int klane = (l >> 4) << 4;
    s16x8 a[2];
#pragma unroll
    for (int K32 = 0; K32 < 2; ++K32)
        a[K32] = As[(arow * 128 + ((K32 * 64 + klane) ^ sw)) >> 4];

    const int r0 = bm + wid * 16 + (l >> 4) * 4;  // + j
#pragma unroll
    for (int ct = 0; ct < 4; ++ct) {
        f32x4 acc[8];
#pragma unroll
        for (int pf = 0; pf < 8; ++pf) acc[pf] = (f32x4)0.f;
#pragma unroll
        for (int K32 = 0; K32 < 2; ++K32)
#pragma unroll
            for (int pf = 0; pf < 8; ++pf) {
                s16x8 b = w1p8[(((size_t)(ct * 8 + pf)) * 2 + K32) * 64 + l];
                acc[pf] = __builtin_amdgcn_mfma_f32_16x16x32_bf16(a[K32], b, acc[pf], 0, 0, 0);
            }
#pragma unroll
        for (int pf = 0; pf < 8; ++pf) {
            const int c = ct * 128 + pf * 16 + (l & 15);
            const float bb = b1[c];
#pragma unroll
            for (int j = 0; j < 4; ++j)
                h2b[(size_t)(r0 + j) * D_DIM + c] = f2bf(fmaxf(acc[pf][j] + bb, 0.f));
        }
    }
}

// ---------------------------------------------------------------------------
// K3 (MFMA): mu/logvar + reparameterize + KL.  BM=32, 4 blocks/CU.
// ---------------------------------------------------------------------------
__global__ __launch_bounds__(256, 4) void k_muvar(const unsigned short* __restrict__ h2b,
                                                  const unsigned short* __restrict__ wmP,
                                                  const unsigned short* __restrict__ wvP,
                                                  const float* __restrict__ bmu,
                                                  const float* __restrict__ bvar,
                                                  const float* __restrict__ eps,
                                                  float* __restrict__ lat,
                                                  float* __restrict__ div_acc) {
    __shared__ s16x8 Hs[2048];  // 32 rows x 512 bf16, 32 KB
    __shared__ float red[4];
    const int tid = threadIdx.x;
    const int l = tid & 63, wid = tid >> 6;
    const int bm = blockIdx.x * 32;

    {
        const int row = tid >> 3, sub = tid & 7;
        const s16x8* src = (const s16x8*)(h2b + (size_t)(bm + row) * D_DIM) + sub * 8;
        const int rb = row * 1024, sw0 = (row & 7) << 4;
#pragma unroll
        for (int it = 0; it < 8; ++it) {
            s16x8 v = src[it];
            int kbyte = sub * 128 + it * 16;
            Hs[(rb + (kbyte ^ sw0)) >> 4] = v;
        }
    }
    __syncthreads();

    const s16x8* wm8 = (const s16x8*)wmP;
    const s16x8* wv8 = (const s16x8*)wvP;
    const int klane = (l >> 4) << 4;
    const int sw = (l & 7) << 4;
    int aoff[2];
#pragma unroll
    for (int m = 0; m < 2; ++m) aoff[m] = (m * 16 + (l & 15)) * 1024;

    float kl = 0.f;
    for (int dt = 0; dt < 4; ++dt) {
        const int dbase = dt * 128 + wid * 32;
        const int P16 = dbase >> 4;
        f32x4 aM[2][2], aV[2][2];
#pragma unroll
        for (int m = 0; m < 2; ++m)
#pragma unroll
            for (int f = 0; f < 2; ++f) { aM[m][f] = (f32x4)0.f; aV[m][f] = (f32x4)0.f; }

#pragma unroll
        for (int K32 = 0; K32 < 16; ++K32) {
            s16x8 bM[2], bV[2];
#pragma unroll
            for (int f = 0; f < 2; ++f) {
                bM[f] = wm8[((size_t)(P16 + f) * 16 + K32) * 64 + l];
                bV[f] = wv8[((size_t)(P16 + f) * 16 + K32) * 64 + l];
            }
            const int kb = ((K32 << 6) + klane) ^ sw;
            s16x8 a[2];
#pragma unroll
            for (int m = 0; m < 2; ++m) a[m] = Hs[(aoff[m] + kb) >> 4];
#pragma unroll
            for (int m = 0; m < 2; ++m)
#pragma unroll
                for (int f = 0; f < 2; ++f) {
                    aM[m][f] = __builtin_amdgcn_mfma_f32_16x16x32_bf16(a[m], bM[f], aM[m][f], 0, 0, 0);
                    aV[m][f] = __builtin_amdgcn_mfma_f32_16x16x32_bf16(a[m], bV[f], aV[m][f], 0, 0, 0);
                }
        }
#pragma unroll
        for (int m = 0; m < 2; ++m)
#pragma unroll
            for (int f = 0; f < 2; ++f) {
                const int d = dbase + f * 16 + (l & 15);
                const float bmv = bmu[d], bvv = bvar[d];
#pragma unroll
                for (int j = 0; j < 4; ++j) {
                    const int row = bm + m * 16 + (l >> 4) * 4 + j;
                    float mu = aM[m][f][j] + bmv;
                    float lv = aV[m][f][j] + bvv;
                    float el = __expf(lv);
                    float la = fmaf(eps[(size_t)row * D_DIM + d], __expf(0.5f * lv), mu);
                    lat[(size_t)row * D_DIM + d] = la;
                    kl += mu * mu + el - lv - 1.f;
                }
            }
    }
    kl *= 0.5f;
#pragma unroll
    for (int m = 1; m < 64; m <<= 1) kl += __shfl_xor(kl, m);
    if (l == 0) red[wid] = kl;
    __syncthreads();
    if (tid == 0) atomicAdd(div_acc, red[0] + red[1] + red[2] + red[3]);
}

// ---------------------------------------------------------------------------
// K4a: pnorm[p] = sum_d protos[p,d]^2
// ---------------------------------------------------------------------------
__global__ __launch_bounds__(256) void k_pnorm(const float* __restrict__ protos,
                                               float* __restrict__ pnorm) {
    const int p = blockIdx.x * 4 + (threadIdx.x >> 6);
    const int lane = threadIdx.x & 63;
    const float* row = protos + (size_t)p * D_DIM;
    float4 v1 = *(const float4*)(row + lane * 8);
    float4 v2 = *(const float4*)(row + lane * 8 + 4);
    float s = v1.x * v1.x + v1.y * v1.y + v1.z * v1.z + v1.w * v1.w +
              v2.x * v2.x + v2.y * v2.y + v2.z * v2.z + v2.w * v2.w;
#pragma unroll
    for (int m = 1; m < 64; m <<= 1) s += __shfl_xor(s, m);
    if (lane == 0) pnorm[p] = s;
}

// ---------------------------------------------------------------------------
// K4 (MFMA): per-row softmax stats + argmax + soft accumulation.
// BM=32 rows/block, 4 blocks/CU, 4 waves x 64 protos/tile.
// ---------------------------------------------------------------------------
__device__ __forceinline__ void vq_tile(const s16x8* __restrict__ Ls,
                                        const s16x8* __restrict__ bpk,
                                        int P16, int l, int klane, int sw,
                                        const int aoff[2], f32x4 acc[2][4]) {
#pragma unroll
    for (int K32 = 0; K32 < 16; ++K32) {
        s16x8 b[4];
#pragma unroll
        for (int pf = 0; pf < 4; ++pf) b[pf] = bpk[((size_t)(P16 + pf) * 16 + K32) * 64 + l];
        const int kb = ((K32 << 6) + klane) ^ sw;
        s16x8 a[2];
#pragma unroll
        for (int m = 0; m < 2; ++m) a[m] = Ls[(aoff[m] + kb) >> 4];
#pragma unroll
        for (int m = 0; m < 2; ++m)
#pragma unroll
            for (int pf = 0; pf < 4; ++pf)
                acc[m][pf] = __builtin_amdgcn_mfma_f32_16x16x32_bf16(a[m], b[pf], acc[m][pf], 0, 0, 0);
    }
}

__global__ __launch_bounds__(256, 4) void k_vq(const float* __restrict__ lat,
                                               const unsigned short* __restrict__ ppack,
                                               const float* __restrict__ pnorm,
                                               int* __restrict__ idxOut,
                                               float* __restrict__ soft_acc) {
    __shared__ s16x8 Ls[2048];  // 32 KB
    __shared__ float rS[4][32];
    __shared__ float rM[4][32];
    __shared__ int rI[4][32];
    __shared__ float invS[32];
    const int tid = threadIdx.x;
    const int l = tid & 63, wid = tid >> 6;
    const int bm = blockIdx.x * 32;

    {
        const int row = tid >> 3, sub = tid & 7;
        const float* src = lat + (size_t)(bm + row) * D_DIM + sub * 64;
        const int rb = row * 1024, sw0 = (row & 7) << 4;
#pragma unroll
        for (int it = 0; it < 8; ++it) {
            float4 a = *(const float4*)(src + it * 8);
            float4 b = *(const float4*)(src + it * 8 + 4);
            s16x8 o;
            o[0] = (short)f2bf(a.x); o[1] = (short)f2bf(a.y);
            o[2] = (short)f2bf(a.z); o[3] = (short)f2bf(a.w);
            o[4] = (short)f2bf(b.x); o[5] = (short)f2bf(b.y);
            o[6] = (short)f2bf(b.z); o[7] = (short)f2bf(b.w);
            int kbyte = sub * 128 + it * 16;
            Ls[(rb + (kbyte ^ sw0)) >> 4] = o;
        }
    }
    __syncthreads();

    const s16x8* ppk = (const s16x8*)ppack;
    const int klane = (l >> 4) << 4;
    const int sw = (l & 7) << 4;
    int aoff[2];
#pragma unroll
    for (int m = 0; m < 2; ++m) aoff[m] = (m * 16 + (l & 15)) * 1024;

    float s_sum[2][4], mv[2][4];
    int mi[2][4];
#pragma unroll
    for (int m = 0; m < 2; ++m)
#pragma unroll
        for (int j = 0; j < 4; ++j) { s_sum[m][j] = 0.f; mv[m][j] = -1e30f; mi[m][j] = 0x7fffffff; }

    // ---------------- sweep 0: sumexp + argmax ----------------
    for (int t = 0; t < 8; ++t) {
        const int pbase = t * 256 + wid * 64;
        const int P16 = pbase >> 4;
        float pn[4];
#pragma unroll
        for (int pf = 0; pf < 4; ++pf) pn[pf] = pnorm[pbase + pf * 16 + (l & 15)];
        f32x4 acc[2][4];
#pragma unroll
        for (int m = 0; m < 2; ++m)
#pragma unroll
            for (int pf = 0; pf < 4; ++pf) acc[m][pf] = (f32x4)0.f;
        vq_tile(Ls, ppk, P16, l, klane, sw, aoff, acc);
#pragma unroll
        for (int m = 0; m < 2; ++m)
#pragma unroll
            for (int pf = 0; pf < 4; ++pf) {
                const int p = pbase + pf * 16 + (l & 15);
#pragma unroll
                for (int j = 0; j < 4; ++j) {
                    float g = 2.f * acc[m][pf][j] - pn[pf];
                    s_sum[m][j] += __expf(g);
                    if (g > mv[m][j] || (g == mv[m][j] && p < mi[m][j])) { mv[m][j] = g; mi[m][j] = p; }
                }
            }
    }
#pragma unroll
    for (int m = 0; m < 2; ++m)
#pragma unroll
        for (int j = 0; j < 4; ++j) {
            float s = s_sum[m][j];
            float v = mv[m][j];
            int i = mi[m][j];
#pragma unroll
            for (int d = 1; d < 16; d <<= 1) {
                s += __shfl_xor(s, d);
                float ov = __shfl_xor(v, d);
                int oi = __shfl_xor(i, d);
                if (ov > v || (ov == v && oi < i)) { v = ov; i = oi; }
            }
            if ((l & 15) == 0) {
                int row = m * 16 + (l >> 4) * 4 + j;
                rS[wid][row] = s; rM[wid][row] = v; rI[wid][row] = i;
            }
        }
    __syncthreads();
    if (tid < 32) {
        float s = 0.f, v = -1e30f;
        int bi = 0x7fffffff;
#pragma unroll
        for (int w = 0; w < 4; ++w) {
            s += rS[w][tid];
            float ov = rM[w][tid];
            int oi = rI[w][tid];
            if (ov > v || (ov == v && oi < bi)) { v = ov; bi = oi; }
        }
        idxOut[bm + tid] = bi;
        invS[tid] = 1.f / s;
    }
    __syncthreads();
    float is[2][4];
#pragma unroll
    for (int m = 0; m < 2; ++m)
#pragma unroll
        for (int j = 0; j < 4; ++j) is[m][j] = invS[m * 16 + (l >> 4) * 4 + j];

    // ---------------- sweep 1: soft assignment accumulation ----------------
    for (int t = 0; t < 8; ++t) {
        const int pbase = t * 256 + wid * 64;
        const int P16 = pbase >> 4;
        float pn[4];
#pragma unroll
        for (int pf = 0; pf < 4; ++pf) pn[pf] = pnorm[pbase + pf * 16 + (l & 15)];
        f32x4 acc[2][4];
#pragma unroll
        for (int m = 0; m < 2; ++m)
#pragma unroll
            for (int pf = 0; pf < 4; ++pf) acc[m][pf] = (f32x4)0.f;
        vq_tile(Ls, ppk, P16, l, klane, sw, aoff, acc);
        float c[4] = {0.f, 0.f, 0.f, 0.f};
#pragma unroll
        for (int m = 0; m < 2; ++m)
#pragma unroll
            for (int pf = 0; pf < 4; ++pf)
#pragma unroll
                for (int j = 0; j < 4; ++j) {
                    float g = 2.f * acc[m][pf][j] - pn[pf];
                    c[pf] += __expf(g) * is[m][j];
                }
#pragma unroll
        for (int pf = 0; pf < 4; ++pf) {
            c[pf] += __shfl_xor(c[pf], 16);
            c[pf] += __shfl_xor(c[pf], 32);
        }
        if (l < 16) {
#pragma unroll
            for (int pf = 0; pf < 4; ++pf) atomicAdd(&soft_acc[pbase + pf * 16 + l], c[pf]);
        }
    }
}

// ---------------------------------------------------------------------------
// K5: out[r,:] = protos[idx[r],:]  (overwrites latents) + vq partial sums
// ---------------------------------------------------------------------------
__global__ __launch_bounds__(256) void k_quant(const float* __restrict__ protos,
                                               const int* __restrict__ idx,
                                               float* __restrict__ out,
                                               float* __restrict__ vq_acc) {
    const int tid = threadIdx.x;
    const int r = blockIdx.x * 2 + (tid >> 7);
    const int c = (tid & 127) * 4;
    const int p = idx[r];
    float4 q = *(const float4*)(protos + (size_t)p * D_DIM + c);
    float4 lv = *(const float4*)(out + (size_t)r * D_DIM + c);
    float dx = q.x - lv.x, dy = q.y - lv.y, dz = q.z - lv.z, dw = q.w - lv.w;
    float s = dx * dx + dy * dy + dz * dz + dw * dw;
    *(float4*)(out + (size_t)r * D_DIM + c) = q;
#pragma unroll
    for (int m = 1; m < 64; m <<= 1) s += __shfl_xor(s, m);
    __shared__ float red[4];
    if ((tid & 63) == 0) red[tid >> 6] = s;
    __syncthreads();
    if (tid == 0) atomicAdd(vq_acc, red[0] + red[1] + red[2] + red[3]);
}

// ---------------------------------------------------------------------------
// K6: finalize scalars.
// ---------------------------------------------------------------------------
__global__ __launch_bounds__(256) void k_final(const float* __restrict__ soft_acc,
                                               const float* __restrict__ scal,
                                               float* __restrict__ out) {
    const int tid = threadIdx.x;
    __shared__ float red[256];
    float vals[8];
    float s = 0.f;
#pragma unroll
    for (int i = 0; i < 8; ++i) {
        float v = soft_acc[tid * 8 + i] * (1.0f / B_N) + 1e-6f;
        vals[i] = v;
        s += v;
    }
    red[tid] = s;
    __syncthreads();
    for (int off = 128; off > 0; off >>= 1) {
        if (tid < off) red[tid] += red[tid + off];
        __syncthreads();
    }
    float norm = red[0];
    __syncthreads();
    float e = 0.f;
#pragma unroll
    for (int i = 0; i < 8; ++i) {
        float p = vals[i] / norm;
        e -= p * __logf(p);
    }
    red[tid] = e;
    __syncthreads();
    for (int off = 128; off > 0; off >>= 1) {
        if (tid < off) red[tid] += red[tid + off];
        __syncthreads();
    }
    if (tid == 0) {
        float ent = red[0];
        float div = scal[0] * (1.0f / B_N);
        float vq = scal[1] * (1.0f / ((float)B_N * (float)D_DIM));
        float vq_loss = 1.25f * vq + 0.1f * ent;
        float total = 0.01f * div + vq_loss;
        out[(size_t)B_N * D_DIM] = total;
        out[(size_t)B_N * D_DIM + 1] = div;
    }
}

// ---------------------------------------------------------------------------
extern "C" void kernel_launch(void* const* d_in, const int* in_sizes, int n_in,
                              void* d_out, int out_size, void* d_ws, size_t ws_size,
                              hipStream_t stream) {
    const float* x = (const float*)d_in[0];
    const float* W0 = (const float*)d_in[1];
    const float* b0 = (const float*)d_in[2];
    const float* W1 = (const float*)d_in[3];
    const float* b1 = (const float*)d_in[4];
    const float* Wmu = (const float*)d_in[5];
    const float* bmu = (const float*)d_in[6];
    const float* Wvar = (const float*)d_in[7];
    const float* bvar = (const float*)d_in[8];
    const float* protos = (const float*)d_in[9];
    const float* eps = (const float*)d_in[10];
    float* out = (float*)d_out;

    unsigned short* ws = (unsigned short*)d_ws;
    unsigned short* h1b = ws;                                   // B*64 bf16
    unsigned short* h2b = h1b + (size_t)B_N * HID;              // B*512 bf16
    unsigned short* ppack = h2b + (size_t)B_N * D_DIM;          // 2048*512 bf16
    unsigned short* wmpack = ppack + (size_t)P_N * D_DIM;       // 512*512 bf16
    unsigned short* wvpack = wmpack + (size_t)D_DIM * D_DIM;    // 512*512 bf16
    unsigned short* w0pack = wvpack + (size_t)D_DIM * D_DIM;    // 64*1024 bf16
    unsigned short* w1pack = w0pack + (size_t)HID * IN_DIM;     // 512*64 bf16
    float* pnorm = (float*)(w1pack + (size_t)D_DIM * HID);      // 2048 f32
    float* soft = pnorm + P_N;                                  // 2048 f32
    float* scal = soft + P_N;                                   // 2
    int* idx = (int*)(scal + 2);                                // B int

    hipMemsetAsync(soft, 0, (P_N + 2) * sizeof(float), stream);

    k_pack<<<(HID * (IN_DIM / 8) + 255) / 256, 256, 0, stream>>>(W0, w0pack, HID, IN_DIM / 8);
    k_pack<<<(D_DIM * (HID / 8) + 255) / 256, 256, 0, stream>>>(W1, w1pack, D_DIM, HID / 8);
    k_pack<<<(P_N * (D_DIM / 8) + 255) / 256, 256, 0, stream>>>(protos, ppack, P_N, D_DIM / 8);
    k_pack<<<(D_DIM * (D_DIM / 8) + 255) / 256, 256, 0, stream>>>(Wmu, wmpack, D_DIM, D_DIM / 8);
    k_pack<<<(D_DIM * (D_DIM / 8) + 255) / 256, 256, 0, stream>>>(Wvar, wvpack, D_DIM, D_DIM / 8);
    k_pnorm<<<P_N / 4, 256, 0, stream>>>(protos, pnorm);

    k_enc1<<<B_N / 128, 256, 0, stream>>>(x, w0pack, b0, h1b);
    k_enc2<<<B_N / 64, 256, 0, stream>>>(h1b, w1pack, b1, h2b);
    k_muvar<<<B_N / 32, 256, 0, stream>>>(h2b, wmpack, wvpack, bmu, bvar, eps, out, scal);
    k_vq<<<B_N / 32, 256, 0, stream>>>(out, ppack, pnorm, idx, soft);
    k_quant<<<B_N / 2, 256, 0, stream>>>(protos, idx, out, scal + 1);
    k_final<<<1, 256, 0, stream>>>(soft, scal, out);
}